// Round 8
// baseline (234.580 us; speedup 1.0000x reference)
//
#include <hip/hip_runtime.h>
#include <math.h>

// ---------------- problem constants ----------------
#define SR        32000
#define NFFT      1024
#define HOP       320
#define NMELS     128
#define NFREQS    513      // NFFT/2 + 1
#define LIN       128000   // samples per batch item
#define PADL      512      // NFFT/2 reflect pad
#define TFRAMES   401
#define NB        128      // batch

// ws layout (float indices):
//   win      : [1024]                      @ 0
//   fb       : [NFREQS][NMELS] = 65664     @ 1024      ([f][m], coalesced for mel loop)
//   fstart   : [128] ints                  @ 66688
//   fend     : [128] ints                  @ 66816
//   T1       : [64][16] float2 = 2048      @ 66944     (W1024^{t*k1})
//   T2       : [4][16]  float2 = 128       @ 68992     (W64^{s*k2})
//   partials : [128*4*2] doubles = 2048 fl @ 69120     (8B aligned)
//   mel      : [NB*TFRAMES*NMELS]          @ 71168     (layout [B][T][M])
#define WS_WIN    0
#define WS_FB     1024
#define WS_FS     66688
#define WS_FE     66816
#define WS_T1     66944
#define WS_T2     68992
#define WS_PART   69120
#define WS_MEL    71168

// ---------------- kernel 1: prep (window + fb + bounds + twiddle tables, fp64) ----------------
__global__ void prep_kernel(float* __restrict__ win, float* __restrict__ fb,
                            int* __restrict__ fstart, int* __restrict__ fend,
                            float2* __restrict__ T1, float2* __restrict__ T2) {
    const int tid = threadIdx.x;                // 256 threads, 1 block

    for (int i = tid; i < NFFT; i += 256) {
        double ang = 2.0 * M_PI * (double)i / (double)NFFT;
        win[i] = (float)(0.5 - 0.5 * cos(ang));    // periodic hann
    }

    // T1: W1024^{t*k1}, t=0..63, k1=0..15
    for (int idx = tid; idx < 1024; idx += 256) {
        int tt = idx >> 4, k1 = idx & 15;
        double ang = -2.0 * M_PI * (double)(tt * k1) / 1024.0;
        T1[idx] = make_float2((float)cos(ang), (float)sin(ang));
    }
    // T2: W64^{s*k2}, s=0..3, k2=0..15
    if (tid < 64) {
        int s = tid >> 4, k2 = tid & 15;
        double ang = -2.0 * M_PI * (double)(s * k2) / 64.0;
        T2[tid] = make_float2((float)cos(ang), (float)sin(ang));
    }

    if (tid < NMELS) {
        const int m = tid;
        const double mel_max = 2595.0 * log10(1.0 + ((double)SR * 0.5) / 700.0);
        const double m0 = (double)(m)     * mel_max / (double)(NMELS + 1);
        const double m1 = (double)(m + 1) * mel_max / (double)(NMELS + 1);
        const double m2 = (double)(m + 2) * mel_max / (double)(NMELS + 1);
        const double f0 = 700.0 * (pow(10.0, m0 / 2595.0) - 1.0);
        const double f1 = 700.0 * (pow(10.0, m1 / 2595.0) - 1.0);
        const double f2 = 700.0 * (pow(10.0, m2 / 2595.0) - 1.0);
        const double binw = (double)SR * 0.5 / (double)(NFREQS - 1);   // 31.25
        int fs = (int)(f0 / binw) + 1;
        int fe = (int)ceil(f2 / binw);
        fs = (fs > 0) ? fs - 1 : 0;            // widen by 1 for fp-rounding safety
        fe = (fe < NFREQS) ? fe + 1 : NFREQS;
        for (int f = fs; f < fe; ++f) {
            double freq = (double)f * binw;
            double down = (freq - f0) / (f1 - f0);
            double up   = (f2 - freq) / (f2 - f1);
            double v = fmin(down, up);
            v = fmax(0.0, v);
            fb[f * NMELS + m] = (float)v;
        }
        fstart[m] = fs;
        fend[m]   = fe;
    }
}

// ---------------- register DFT-16 (radix-4 x radix-4, forward) ----------------
__device__ __forceinline__ void dft16(float (&xr)[16], float (&xi)[16]) {
    const float C8 = 0.92387953251128674f;
    const float S8 = 0.38268343236508978f;
    const float R2 = 0.70710678118654752f;
    const float WR[4][4] = {{1,1,1,1},{1, C8, R2, S8},{1, R2, 0.f,-R2},{1, S8,-R2,-C8}};
    const float WI[4][4] = {{0,0,0,0},{0,-S8,-R2,-C8},{0,-R2,-1.f,-R2},{0,-C8,-R2, S8}};
    float pr[4][4], pi[4][4];
#pragma unroll
    for (int j0 = 0; j0 < 4; ++j0) {
        float ar = xr[j0],      ai = xi[j0];
        float br = xr[j0 + 4],  bi = xi[j0 + 4];
        float cr = xr[j0 + 8],  ci = xi[j0 + 8];
        float dr = xr[j0 + 12], di = xi[j0 + 12];
        float t0r = ar + cr, t0i = ai + ci;
        float t1r = ar - cr, t1i = ai - ci;
        float t2r = br + dr, t2i = bi + di;
        float t3r = br - dr, t3i = bi - di;
        pr[j0][0] = t0r + t2r; pi[j0][0] = t0i + t2i;
        pr[j0][1] = t1r + t3i; pi[j0][1] = t1i - t3r;
        pr[j0][2] = t0r - t2r; pi[j0][2] = t0i - t2i;
        pr[j0][3] = t1r - t3i; pi[j0][3] = t1i + t3r;
    }
#pragma unroll
    for (int ka = 0; ka < 4; ++ka) {
        float q0r = pr[0][ka], q0i = pi[0][ka];
        float q1r = pr[1][ka] * WR[1][ka] - pi[1][ka] * WI[1][ka];
        float q1i = pr[1][ka] * WI[1][ka] + pi[1][ka] * WR[1][ka];
        float q2r = pr[2][ka] * WR[2][ka] - pi[2][ka] * WI[2][ka];
        float q2i = pr[2][ka] * WI[2][ka] + pi[2][ka] * WR[2][ka];
        float q3r = pr[3][ka] * WR[3][ka] - pi[3][ka] * WI[3][ka];
        float q3i = pr[3][ka] * WI[3][ka] + pi[3][ka] * WR[3][ka];
        float t0r = q0r + q2r, t0i = q0i + q2i;
        float t1r = q0r - q2r, t1i = q0i - q2i;
        float t2r = q1r + q3r, t2i = q1i + q3i;
        float t3r = q1r - q3r, t3i = q1i - q3i;
        xr[ka]      = t0r + t2r; xi[ka]      = t0i + t2i;
        xr[ka + 4]  = t1r + t3i; xi[ka + 4]  = t1i - t3r;
        xr[ka + 8]  = t0r - t2r; xi[ka + 8]  = t0i - t2i;
        xr[ka + 12] = t1r - t3i; xi[ka + 12] = t1i + t3r;
    }
}

// ---------------- kernel 2: wave-resident FFT (16x16x4) -> |X| -> mel ----------------
// one WAVE per packed frame-pair; 4 waves/block; no __syncthreads; XCD-chunked swizzle.
__launch_bounds__(256)
__global__ void fft_mel_kernel(const float* __restrict__ x,
                               const float* __restrict__ win,
                               const float2* __restrict__ T1,
                               const float2* __restrict__ T2,
                               const float* __restrict__ fb,
                               const int* __restrict__ fstart,
                               const int* __restrict__ fend,
                               float* __restrict__ mel) {
    __shared__ __align__(16) float2 buf[4][NFFT];   // per-wave scratch; reused as |X|

    const int w = threadIdx.x >> 6;       // wave in block
    const int t = threadIdx.x & 63;       // lane
    // XCD-chunked bijective swizzle: 6416 blocks = 8 XCDs x 802 contiguous chunks.
    const int bid  = (blockIdx.x & 7) * 802 + (blockIdx.x >> 3);
    const int task = bid * 4 + w;         // 0..25663
    const int q  = task / TFRAMES;
    const int tf = task - q * TFRAMES;
    const float* xb0 = x + (size_t)(2 * q) * LIN;
    const float* xb1 = xb0 + LIN;
    const int base = tf * HOP - PADL;

    // ---- preload this lane's T1 row (16 float2 = 8 float4) into registers ----
    float4 t1v[8];
    {
        const float4* T1v = (const float4*)T1;
#pragma unroll
        for (int r = 0; r < 8; ++r) t1v[r] = T1v[t * 8 + r];
    }

    // ---- load 16 samples/lane (stride 64), windowed, packed z = w*x0 + i*w*x1 ----
    float xr[16], xi[16];
    if (base >= 0 && base + NFFT <= LIN) {          // interior frames (399 of 401)
#pragma unroll
        for (int j = 0; j < 16; ++j) {
            int n = t + 64 * j;
            float wv = win[n];
            xr[j] = xb0[base + n] * wv;
            xi[j] = xb1[base + n] * wv;
        }
    } else {
#pragma unroll
        for (int j = 0; j < 16; ++j) {
            int n = t + 64 * j;
            int p = base + n;
            p = (p < 0) ? -p : p;
            p = (p >= LIN) ? (2 * LIN - 2 - p) : p;
            float wv = win[n];
            xr[j] = xb0[p] * wv;
            xi[j] = xb1[p] * wv;
        }
    }

    // ---- stage 1: DFT-16 over j, twiddle W1024^{t*k1} from registers ----
    dft16(xr, xi);
#pragma unroll
    for (int k1 = 1; k1 < 16; ++k1) {
        const int r = k1 >> 1;
        const float2 wv = (k1 & 1) ? make_float2(t1v[r].z, t1v[r].w)
                                   : make_float2(t1v[r].x, t1v[r].y);
        const float tr = xr[k1] * wv.x - xi[k1] * wv.y;
        xi[k1] = xr[k1] * wv.y + xi[k1] * wv.x;
        xr[k1] = tr;
    }

    // ---- transpose 1 ----
    float2* B = buf[w];
#pragma unroll
    for (int k1 = 0; k1 < 16; ++k1)
        B[k1 * 64 + (t ^ ((k1 & 3) << 2))] = make_float2(xr[k1], xi[k1]);

    const int g = t >> 2, s = t & 3;
    const int c2 = g & 3;
#pragma unroll
    for (int j = 0; j < 16; ++j) {
        float2 v = B[g * 64 + s + 4 * (j ^ c2)];
        xr[j] = v.x; xi[j] = v.y;
    }

    // ---- stage 2: DFT-16 over u, twiddle W64^{s*k2} from table (4 rows, L1-hot) ----
    dft16(xr, xi);
    {
        const float2* __restrict__ Tr = T2 + (s << 4);
#pragma unroll
        for (int k2 = 1; k2 < 16; ++k2) {
            const float2 wv = Tr[k2];
            const float tr = xr[k2] * wv.x - xi[k2] * wv.y;
            xi[k2] = xr[k2] * wv.y + xi[k2] * wv.x;
            xr[k2] = tr;
        }
    }

    // ---- write E at psi(e), e = g*64 + 4*k2 + s, psi = e ^ ((g&7)<<1) ----
    {
        const int g2 = (g & 7) << 1;
#pragma unroll
        for (int k2 = 0; k2 < 16; ++k2)
            B[g * 64 + ((4 * k2 + s) ^ g2)] = make_float2(xr[k2], xi[k2]);
    }

    // ---- final radix-4 + Hermitian unpack + magnitudes into REGISTERS ----
    const float4* Bv = (const float4*)buf[w];
    const int gk = t & 15;
    const int g2k = (gk & 7) << 1;
    const int tb = t >> 4;
    float m0r[8], m1r[8];
#pragma unroll
    for (int jj = 0; jj < 8; ++jj) {
        const int k  = t + 64 * jj;                 // 0..511
        const int jk = (tb + 4 * jj) & 15;
        const int e0 = gk * 64 + ((4 * jk) ^ g2k);
        float4 E01 = Bv[e0 >> 1];                   // s=0,1
        float4 E23 = Bv[(e0 ^ 2) >> 1];             // s=2,3
        float S02r = E01.x + E23.x, S02i = E01.y + E23.y;
        float D02r = E01.x - E23.x, D02i = E01.y - E23.y;
        float S13r = E01.z + E23.z, S13i = E01.w + E23.w;
        float D13r = E01.z - E23.z, D13i = E01.w - E23.w;
        float a, b;
        if (jj < 4) { a = S02r + S13r; b = S02i + S13i; }          // bk=0
        else        { a = D02r + D13i; b = D02i - D13r; }          // bk=1
        const int kN = (1024 - k) & 1023;
        const int gN = kN & 15, jN = (kN >> 4) & 15, bN = kN >> 8;
        const int eN = gN * 64 + ((4 * jN) ^ ((gN & 7) << 1));
        float4 F01 = Bv[eN >> 1];
        float4 F23 = Bv[(eN ^ 2) >> 1];
        float GS02r = F01.x + F23.x, GS02i = F01.y + F23.y;
        float GD02r = F01.x - F23.x, GD02i = F01.y - F23.y;
        float GS13r = F01.z + F23.z, GS13i = F01.w + F23.w;
        float GD13r = F01.z - F23.z, GD13i = F01.w - F23.w;
        const float sE = (bN & 2) ? -1.0f : 1.0f;
        float cEv = GS02r + sE * GS13r, dEv = GS02i + sE * GS13i;  // even bN
        float cOv = GD02r + sE * GD13i, dOv = GD02i - sE * GD13r;  // odd bN
        float c = (bN & 1) ? cOv : cEv;
        float d = (bN & 1) ? dOv : dEv;
        m0r[jj] = 0.5f * sqrtf((a + c) * (a + c) + (b - d) * (b - d));
        m1r[jj] = 0.5f * sqrtf((b + d) * (b + d) + (c - a) * (c - a));
    }
    float e512a = 0.0f, e512b = 0.0f;
    if (t == 0) {   // k = 512: bin from E group (0,0), bk=2
        float4 E01 = Bv[0], E23 = Bv[1];
        e512a = fabsf((E01.x + E23.x) - (E01.z + E23.z));
        e512b = fabsf((E01.y + E23.y) - (E01.w + E23.w));
    }

    // ---- overwrite buf as |X| array (per-wave DS ordering makes this safe) ----
    float2* mag2 = buf[w];
#pragma unroll
    for (int jj = 0; jj < 8; ++jj)
        mag2[t + 64 * jj] = make_float2(m0r[jj], m1r[jj]);
    if (t == 0) mag2[512] = make_float2(e512a, e512b);

    // ---- sparse mel projection; fb[f][m] -> coalesced across lanes ----
#pragma unroll
    for (int h = 0; h < 2; ++h) {
        const int m = t + 64 * h;
        const int fs = fstart[m], fe = fend[m];
        const float* fr = fb + m;
        float a0 = 0.0f, a1 = 0.0f;
        for (int f = fs; f < fe; ++f) {
            float2 mg = mag2[f];
            float cf = fr[f * NMELS];
            a0 = fmaf(mg.x, cf, a0);
            a1 = fmaf(mg.y, cf, a1);
        }
        mel[((size_t)(2 * q)     * TFRAMES + tf) * NMELS + m] = a0;
        mel[((size_t)(2 * q + 1) * TFRAMES + tf) * NMELS + m] = a1;
    }
}

// ---------------- kernel 3: PCEN chunked-scan (R3 structure, 512 blocks) ----------------
#define CHUNKS 8
#define CH0LEN 51            // 401 = 51 + 7*50
#define CHLEN  50
#define AFACT  0.2819890f    // 0.975^50 (exact to fp32)

__launch_bounds__(256)
__global__ void pcen_kernel(const float* __restrict__ mel,
                            float* __restrict__ out,
                            double* __restrict__ partials) {
    const int b   = blockIdx.x >> 2;
    const int mg  = blockIdx.x & 3;
    const int tid = threadIdx.x;
    const int ml  = tid & 31;
    const int c   = tid >> 5;                       // 0..7
    const int m   = mg * 32 + ml;
    const int t0  = (c == 0) ? 0 : (CH0LEN + CHLEN * (c - 1));
    const int len = (c == 0) ? CH0LEN : CHLEN;
    const float* mb = mel + (size_t)b * TFRAMES * NMELS;

    float v[CH0LEN];
#pragma unroll
    for (int i = 0; i < CH0LEN; ++i)
        if (i < len) v[i] = mb[(size_t)(t0 + i) * NMELS + m];

    // pass 1: per-chunk IIR partial with zero carry-in (chunk 0 = true init)
    float M;
    if (c == 0) {
        M = v[0];
#pragma unroll
        for (int i = 1; i < CH0LEN; ++i) M = fmaf(0.975f, M, 0.025f * v[i]);
    } else {
        M = 0.0f;
#pragma unroll
        for (int i = 0; i < CHLEN; ++i) M = fmaf(0.975f, M, 0.025f * v[i]);
    }
    __shared__ float Bc[CHUNKS][32];
    Bc[c][ml] = M;
    __syncthreads();

    // fold carries: M_in(c) = B_{c-1} + A*(B_{c-2} + ...)   (A = 0.975^50)
    float Min = 0.0f;
    if (c > 0) {
        Min = Bc[0][ml];
        for (int k = 1; k < c; ++k) Min = fmaf(AFACT, Min, Bc[k][ml]);
    }

    // pass 2: exact replay from carry; pcen (division-free); stats; store
    M = Min;
    float sum = 0.0f, sumsq = 0.0f;
    float* orow = out + (size_t)b * NMELS * TFRAMES + (size_t)m * TFRAMES + t0;
#pragma unroll
    for (int i = 0; i < CH0LEN; ++i) {
        if (i < len) {
            float xt = v[i];
            M = (c == 0 && i == 0) ? xt : fmaf(0.975f, M, 0.025f * xt);
            float rsm = __expf(-0.98f * __logf(1e-6f + M));   // (eps+M)^-0.98
            float p = sqrtf(fmaf(xt, rsm, 2.0f)) - 1.4142135623730951f;
            orow[i] = p;
            sum += p;
            sumsq = fmaf(p, p, sumsq);
        }
    }

    // block reduction (fp64) -> unique partial slot
    double s = (double)sum, qq = (double)sumsq;
    for (int off = 32; off > 0; off >>= 1) {
        s  += __shfl_down(s, off);
        qq += __shfl_down(qq, off);
    }
    __shared__ double wsum[4], wsq[4];
    const int wid = tid >> 6, lane = tid & 63;
    if (lane == 0) { wsum[wid] = s; wsq[wid] = qq; }
    __syncthreads();
    if (tid == 0) {
        double S = wsum[0] + wsum[1] + wsum[2] + wsum[3];
        double Q = wsq[0] + wsq[1] + wsq[2] + wsq[3];
        partials[(size_t)(b * 4 + mg) * 2]     = S;
        partials[(size_t)(b * 4 + mg) * 2 + 1] = Q;
    }
}

// ---------------- kernel 4: normalize (full GPU, float4) ----------------
__global__ void norm_kernel(float* __restrict__ out, const double* __restrict__ partials) {
    __shared__ float sh[2];
    const int b = blockIdx.x;
    if (threadIdx.x == 0) {
        double S = 0.0, Q = 0.0;
#pragma unroll
        for (int gg = 0; gg < 4; ++gg) {
            S += partials[(size_t)(b * 4 + gg) * 2];
            Q += partials[(size_t)(b * 4 + gg) * 2 + 1];
        }
        const double n = (double)(NMELS * TFRAMES);
        double mean = S / n;
        double var  = (Q - n * mean * mean) / (n - 1.0);
        double sd   = sqrt(var > 0.0 ? var : 0.0);
        sh[0] = (float)mean;
        sh[1] = (float)(1.0 / (sd + 1e-6));
    }
    __syncthreads();
    const int i4 = blockIdx.y * 256 + threadIdx.x;
    if (i4 >= NMELS * TFRAMES / 4) return;          // 12832
    const float mean = sh[0], inv = sh[1];
    float4* o = (float4*)(out + (size_t)b * NMELS * TFRAMES);
    float4 vv = o[i4];
    vv.x = (vv.x - mean) * inv;
    vv.y = (vv.y - mean) * inv;
    vv.z = (vv.z - mean) * inv;
    vv.w = (vv.w - mean) * inv;
    o[i4] = vv;
}

// ---------------- launch ----------------
extern "C" void kernel_launch(void* const* d_in, const int* in_sizes, int n_in,
                              void* d_out, int out_size, void* d_ws, size_t ws_size,
                              hipStream_t stream) {
    const float* x = (const float*)d_in[0];
    float* out = (float*)d_out;
    float* ws  = (float*)d_ws;

    float*  win    = ws + WS_WIN;
    float*  fb     = ws + WS_FB;
    int*    fstart = (int*)(ws + WS_FS);
    int*    fend   = (int*)(ws + WS_FE);
    float2* T1     = (float2*)(ws + WS_T1);
    float2* T2     = (float2*)(ws + WS_T2);
    double* parts  = (double*)(ws + WS_PART);
    float*  mel    = ws + WS_MEL;

    prep_kernel<<<dim3(1), dim3(256), 0, stream>>>(win, fb, fstart, fend, T1, T2);
    fft_mel_kernel<<<dim3((NB / 2) * TFRAMES / 4), dim3(256), 0, stream>>>(
        x, win, T1, T2, fb, fstart, fend, mel);
    pcen_kernel<<<dim3(NB * 4), dim3(256), 0, stream>>>(mel, out, parts);
    norm_kernel<<<dim3(NB, 51), dim3(256), 0, stream>>>(out, parts);
}

// Round 9
// 190.310 us; speedup vs baseline: 1.2326x; 1.2326x over previous
//
#include <hip/hip_runtime.h>
#include <math.h>

// ---------------- problem constants ----------------
#define SR        32000
#define NFFT      1024
#define HOP       320
#define NMELS     128
#define NFREQS    513      // NFFT/2 + 1
#define LIN       128000   // samples per batch item
#define PADL      512      // NFFT/2 reflect pad
#define TFRAMES   401
#define NB        128      // batch
#define FBW       32       // packed filter width (max true width ~30)

// ws layout (float indices):
//   win      : [1024]                      @ 0
//   fbpackT  : [32][128] = 4096            @ 1024    ([i][m]: coalesced across lanes)
//   fstart   : [128] ints                  @ 5120
//   T1       : [64][16] float2 = 2048      @ 5248    (W1024^{t*k1})
//   T2       : [4][16]  float2 = 128       @ 7296    (W64^{s*k2})
//   partials : [128*4*2] doubles = 2048 fl @ 7424    (byte off 29696, 8B aligned)
//   mel      : [NB*TFRAMES*NMELS]          @ 9472    (layout [B][T][M])
#define WS_WIN    0
#define WS_FBP    1024
#define WS_FS     5120
#define WS_T1     5248
#define WS_T2     7296
#define WS_PART   7424
#define WS_MEL    9472

// ---------------- kernel 1: prep, 9 blocks ----------------
// blocks 0-3: window; 4-7: T1; 8: T2 + packed filterbank
__global__ void prep_kernel(float* __restrict__ win, float* __restrict__ fbpackT,
                            int* __restrict__ fstart,
                            float2* __restrict__ T1, float2* __restrict__ T2) {
    const int b   = blockIdx.x;
    const int tid = threadIdx.x;                // 256 threads

    if (b < 4) {
        const int i = b * 256 + tid;            // 0..1023
        double ang = 2.0 * M_PI * (double)i / (double)NFFT;
        win[i] = (float)(0.5 - 0.5 * cos(ang)); // periodic hann
        return;
    }
    if (b < 8) {
        const int idx = (b - 4) * 256 + tid;    // 0..1023
        int tt = idx >> 4, k1 = idx & 15;
        double ang = -2.0 * M_PI * (double)(tt * k1) / 1024.0;
        T1[idx] = make_float2((float)cos(ang), (float)sin(ang));
        return;
    }
    // block 8
    if (tid < 64) {
        int s = tid >> 4, k2 = tid & 15;
        double ang = -2.0 * M_PI * (double)(s * k2) / 64.0;
        T2[tid] = make_float2((float)cos(ang), (float)sin(ang));
    }
    if (tid < NMELS) {
        const int m = tid;
        const double mel_max = 2595.0 * log10(1.0 + ((double)SR * 0.5) / 700.0);
        const double m0 = (double)(m)     * mel_max / (double)(NMELS + 1);
        const double m1 = (double)(m + 1) * mel_max / (double)(NMELS + 1);
        const double m2 = (double)(m + 2) * mel_max / (double)(NMELS + 1);
        const double f0 = 700.0 * (pow(10.0, m0 / 2595.0) - 1.0);
        const double f1 = 700.0 * (pow(10.0, m1 / 2595.0) - 1.0);
        const double f2 = 700.0 * (pow(10.0, m2 / 2595.0) - 1.0);
        const double binw = (double)SR * 0.5 / (double)(NFREQS - 1);   // 31.25
        int fs = (int)(f0 / binw);              // floor(f0/binw)+1 widened by 1
        if (fs < 0) fs = 0;
        int fe = (int)ceil(f2 / binw) + 1;      // exclusive, widened by 1
        if (fe > NFREQS) fe = NFREQS;
        for (int i = 0; i < FBW; ++i) {
            const int f = fs + i;
            float w = 0.0f;
            if (f < fe) {
                double freq = (double)f * binw;
                double down = (freq - f0) / (f1 - f0);
                double up   = (f2 - freq) / (f2 - f1);
                double v = fmin(down, up);
                w = (float)fmax(0.0, v);
            }
            fbpackT[i * NMELS + m] = w;
        }
        fstart[m] = fs;
    }
}

// ---------------- register DFT-16 (radix-4 x radix-4, forward) ----------------
__device__ __forceinline__ void dft16(float (&xr)[16], float (&xi)[16]) {
    const float C8 = 0.92387953251128674f;
    const float S8 = 0.38268343236508978f;
    const float R2 = 0.70710678118654752f;
    const float WR[4][4] = {{1,1,1,1},{1, C8, R2, S8},{1, R2, 0.f,-R2},{1, S8,-R2,-C8}};
    const float WI[4][4] = {{0,0,0,0},{0,-S8,-R2,-C8},{0,-R2,-1.f,-R2},{0,-C8,-R2, S8}};
    float pr[4][4], pi[4][4];
#pragma unroll
    for (int j0 = 0; j0 < 4; ++j0) {
        float ar = xr[j0],      ai = xi[j0];
        float br = xr[j0 + 4],  bi = xi[j0 + 4];
        float cr = xr[j0 + 8],  ci = xi[j0 + 8];
        float dr = xr[j0 + 12], di = xi[j0 + 12];
        float t0r = ar + cr, t0i = ai + ci;
        float t1r = ar - cr, t1i = ai - ci;
        float t2r = br + dr, t2i = bi + di;
        float t3r = br - dr, t3i = bi - di;
        pr[j0][0] = t0r + t2r; pi[j0][0] = t0i + t2i;
        pr[j0][1] = t1r + t3i; pi[j0][1] = t1i - t3r;
        pr[j0][2] = t0r - t2r; pi[j0][2] = t0i - t2i;
        pr[j0][3] = t1r - t3i; pi[j0][3] = t1i + t3r;
    }
#pragma unroll
    for (int ka = 0; ka < 4; ++ka) {
        float q0r = pr[0][ka], q0i = pi[0][ka];
        float q1r = pr[1][ka] * WR[1][ka] - pi[1][ka] * WI[1][ka];
        float q1i = pr[1][ka] * WI[1][ka] + pi[1][ka] * WR[1][ka];
        float q2r = pr[2][ka] * WR[2][ka] - pi[2][ka] * WI[2][ka];
        float q2i = pr[2][ka] * WI[2][ka] + pi[2][ka] * WR[2][ka];
        float q3r = pr[3][ka] * WR[3][ka] - pi[3][ka] * WI[3][ka];
        float q3i = pr[3][ka] * WI[3][ka] + pi[3][ka] * WR[3][ka];
        float t0r = q0r + q2r, t0i = q0i + q2i;
        float t1r = q0r - q2r, t1i = q0i - q2i;
        float t2r = q1r + q3r, t2i = q1i + q3i;
        float t3r = q1r - q3r, t3i = q1i - q3i;
        xr[ka]      = t0r + t2r; xi[ka]      = t0i + t2i;
        xr[ka + 4]  = t1r + t3i; xi[ka + 4]  = t1i - t3r;
        xr[ka + 8]  = t0r - t2r; xi[ka + 8]  = t0i - t2i;
        xr[ka + 12] = t1r - t3i; xi[ka + 12] = t1i + t3r;
    }
}

// ---------------- kernel 2: wave-resident FFT, ONE WAVE PER BLOCK (8KB LDS) ----------------
__launch_bounds__(64)
__global__ void fft_mel_kernel(const float* __restrict__ x,
                               const float* __restrict__ win,
                               const float2* __restrict__ T1,
                               const float2* __restrict__ T2,
                               const float* __restrict__ fbpackT,
                               const int* __restrict__ fstart,
                               float* __restrict__ mel) {
    __shared__ __align__(16) float2 buf[NFFT];   // scratch; reused as |X|

    const int t = threadIdx.x;            // lane 0..63
    // XCD-chunked bijective swizzle: 25664 blocks = 8 XCDs x 3208 chunks.
    const int task = (blockIdx.x & 7) * 3208 + (blockIdx.x >> 3);   // 0..25663
    const int q  = task / TFRAMES;
    const int tf = task - q * TFRAMES;
    const float* xb0 = x + (size_t)(2 * q) * LIN;
    const float* xb1 = xb0 + LIN;
    const int base = tf * HOP - PADL;

    // ---- preload this lane's T1 row (16 float2 = 8 float4) into registers ----
    float4 t1v[8];
    {
        const float4* T1v = (const float4*)T1;
#pragma unroll
        for (int r = 0; r < 8; ++r) t1v[r] = T1v[t * 8 + r];
    }

    // ---- load 16 samples/lane (stride 64), windowed, packed z = w*x0 + i*w*x1 ----
    float xr[16], xi[16];
    if (base >= 0 && base + NFFT <= LIN) {          // interior frames (399 of 401)
#pragma unroll
        for (int j = 0; j < 16; ++j) {
            int n = t + 64 * j;
            float wv = win[n];
            xr[j] = xb0[base + n] * wv;
            xi[j] = xb1[base + n] * wv;
        }
    } else {
#pragma unroll
        for (int j = 0; j < 16; ++j) {
            int n = t + 64 * j;
            int p = base + n;
            p = (p < 0) ? -p : p;
            p = (p >= LIN) ? (2 * LIN - 2 - p) : p;
            float wv = win[n];
            xr[j] = xb0[p] * wv;
            xi[j] = xb1[p] * wv;
        }
    }

    // ---- stage 1: DFT-16 over j, twiddle W1024^{t*k1} from registers ----
    dft16(xr, xi);
#pragma unroll
    for (int k1 = 1; k1 < 16; ++k1) {
        const int r = k1 >> 1;
        const float2 wv = (k1 & 1) ? make_float2(t1v[r].z, t1v[r].w)
                                   : make_float2(t1v[r].x, t1v[r].y);
        const float tr = xr[k1] * wv.x - xi[k1] * wv.y;
        xi[k1] = xr[k1] * wv.y + xi[k1] * wv.x;
        xr[k1] = tr;
    }

    // ---- transpose 1 ----
    float2* B = buf;
#pragma unroll
    for (int k1 = 0; k1 < 16; ++k1)
        B[k1 * 64 + (t ^ ((k1 & 3) << 2))] = make_float2(xr[k1], xi[k1]);

    const int g = t >> 2, s = t & 3;
    const int c2 = g & 3;
#pragma unroll
    for (int j = 0; j < 16; ++j) {
        float2 v = B[g * 64 + s + 4 * (j ^ c2)];
        xr[j] = v.x; xi[j] = v.y;
    }

    // ---- stage 2: DFT-16 over u, twiddle W64^{s*k2} from table (4 rows, L1-hot) ----
    dft16(xr, xi);
    {
        const float2* __restrict__ Tr = T2 + (s << 4);
#pragma unroll
        for (int k2 = 1; k2 < 16; ++k2) {
            const float2 wv = Tr[k2];
            const float tr = xr[k2] * wv.x - xi[k2] * wv.y;
            xi[k2] = xr[k2] * wv.y + xi[k2] * wv.x;
            xr[k2] = tr;
        }
    }

    // ---- write E at psi(e), e = g*64 + 4*k2 + s, psi = e ^ ((g&7)<<1) ----
    {
        const int g2 = (g & 7) << 1;
#pragma unroll
        for (int k2 = 0; k2 < 16; ++k2)
            B[g * 64 + ((4 * k2 + s) ^ g2)] = make_float2(xr[k2], xi[k2]);
    }

    // ---- final radix-4 + Hermitian unpack + magnitudes into REGISTERS ----
    const float4* Bv = (const float4*)buf;
    const int gk = t & 15;
    const int g2k = (gk & 7) << 1;
    const int tb = t >> 4;
    float m0r[8], m1r[8];
#pragma unroll
    for (int jj = 0; jj < 8; ++jj) {
        const int k  = t + 64 * jj;                 // 0..511
        const int jk = (tb + 4 * jj) & 15;
        const int e0 = gk * 64 + ((4 * jk) ^ g2k);
        float4 E01 = Bv[e0 >> 1];                   // s=0,1
        float4 E23 = Bv[(e0 ^ 2) >> 1];             // s=2,3
        float S02r = E01.x + E23.x, S02i = E01.y + E23.y;
        float D02r = E01.x - E23.x, D02i = E01.y - E23.y;
        float S13r = E01.z + E23.z, S13i = E01.w + E23.w;
        float D13r = E01.z - E23.z, D13i = E01.w - E23.w;
        float a, b;
        if (jj < 4) { a = S02r + S13r; b = S02i + S13i; }          // bk=0
        else        { a = D02r + D13i; b = D02i - D13r; }          // bk=1
        const int kN = (1024 - k) & 1023;
        const int gN = kN & 15, jN = (kN >> 4) & 15, bN = kN >> 8;
        const int eN = gN * 64 + ((4 * jN) ^ ((gN & 7) << 1));
        float4 F01 = Bv[eN >> 1];
        float4 F23 = Bv[(eN ^ 2) >> 1];
        float GS02r = F01.x + F23.x, GS02i = F01.y + F23.y;
        float GD02r = F01.x - F23.x, GD02i = F01.y - F23.y;
        float GS13r = F01.z + F23.z, GS13i = F01.w + F23.w;
        float GD13r = F01.z - F23.z, GD13i = F01.w - F23.w;
        const float sE = (bN & 2) ? -1.0f : 1.0f;
        float cEv = GS02r + sE * GS13r, dEv = GS02i + sE * GS13i;  // even bN
        float cOv = GD02r + sE * GD13i, dOv = GD02i - sE * GD13r;  // odd bN
        float c = (bN & 1) ? cOv : cEv;
        float d = (bN & 1) ? dOv : dEv;
        m0r[jj] = 0.5f * sqrtf((a + c) * (a + c) + (b - d) * (b - d));
        m1r[jj] = 0.5f * sqrtf((b + d) * (b + d) + (c - a) * (c - a));
    }
    float e512a = 0.0f, e512b = 0.0f;
    if (t == 0) {   // k = 512: bin from E group (0,0), bk=2
        float4 E01 = Bv[0], E23 = Bv[1];
        e512a = fabsf((E01.x + E23.x) - (E01.z + E23.z));
        e512b = fabsf((E01.y + E23.y) - (E01.w + E23.w));
    }

    // ---- overwrite buf as |X| array (per-wave DS ordering makes this safe) ----
    float2* mag2 = buf;
#pragma unroll
    for (int jj = 0; jj < 8; ++jj)
        mag2[t + 64 * jj] = make_float2(m0r[jj], m1r[jj]);
    if (t == 0) mag2[512] = make_float2(e512a, e512b);

    // ---- mel projection: uniform 32-trip loop, coalesced fbpackT reads ----
#pragma unroll
    for (int h = 0; h < 2; ++h) {
        const int m = t + 64 * h;
        const int fs = fstart[m];
        float a0 = 0.0f, a1 = 0.0f;
#pragma unroll
        for (int i = 0; i < FBW; ++i) {
            const float cf = fbpackT[i * NMELS + m];   // lanes consecutive: 4 lines
            int f = fs + i;
            f = (f > 512) ? 512 : f;                   // clamp; cf==0 there
            const float2 mg = mag2[f];
            a0 = fmaf(mg.x, cf, a0);
            a1 = fmaf(mg.y, cf, a1);
        }
        mel[((size_t)(2 * q)     * TFRAMES + tf) * NMELS + m] = a0;
        mel[((size_t)(2 * q + 1) * TFRAMES + tf) * NMELS + m] = a1;
    }
}

// ---------------- kernel 3: PCEN chunked-scan (R3 structure, 512 blocks) ----------------
#define CHUNKS 8
#define CH0LEN 51            // 401 = 51 + 7*50
#define CHLEN  50
#define AFACT  0.2819890f    // 0.975^50 (exact to fp32)

__launch_bounds__(256)
__global__ void pcen_kernel(const float* __restrict__ mel,
                            float* __restrict__ out,
                            double* __restrict__ partials) {
    const int b   = blockIdx.x >> 2;
    const int mg  = blockIdx.x & 3;
    const int tid = threadIdx.x;
    const int ml  = tid & 31;
    const int c   = tid >> 5;                       // 0..7
    const int m   = mg * 32 + ml;
    const int t0  = (c == 0) ? 0 : (CH0LEN + CHLEN * (c - 1));
    const int len = (c == 0) ? CH0LEN : CHLEN;
    const float* mb = mel + (size_t)b * TFRAMES * NMELS;

    float v[CH0LEN];
#pragma unroll
    for (int i = 0; i < CH0LEN; ++i)
        if (i < len) v[i] = mb[(size_t)(t0 + i) * NMELS + m];

    // pass 1: per-chunk IIR partial with zero carry-in (chunk 0 = true init)
    float M;
    if (c == 0) {
        M = v[0];
#pragma unroll
        for (int i = 1; i < CH0LEN; ++i) M = fmaf(0.975f, M, 0.025f * v[i]);
    } else {
        M = 0.0f;
#pragma unroll
        for (int i = 0; i < CHLEN; ++i) M = fmaf(0.975f, M, 0.025f * v[i]);
    }
    __shared__ float Bc[CHUNKS][32];
    Bc[c][ml] = M;
    __syncthreads();

    // fold carries: M_in(c) = B_{c-1} + A*(B_{c-2} + ...)   (A = 0.975^50)
    float Min = 0.0f;
    if (c > 0) {
        Min = Bc[0][ml];
        for (int k = 1; k < c; ++k) Min = fmaf(AFACT, Min, Bc[k][ml]);
    }

    // pass 2: exact replay from carry; pcen (division-free); stats; store
    M = Min;
    float sum = 0.0f, sumsq = 0.0f;
    float* orow = out + (size_t)b * NMELS * TFRAMES + (size_t)m * TFRAMES + t0;
#pragma unroll
    for (int i = 0; i < CH0LEN; ++i) {
        if (i < len) {
            float xt = v[i];
            M = (c == 0 && i == 0) ? xt : fmaf(0.975f, M, 0.025f * xt);
            float rsm = __expf(-0.98f * __logf(1e-6f + M));   // (eps+M)^-0.98
            float p = sqrtf(fmaf(xt, rsm, 2.0f)) - 1.4142135623730951f;
            orow[i] = p;
            sum += p;
            sumsq = fmaf(p, p, sumsq);
        }
    }

    // block reduction (fp64) -> unique partial slot
    double s = (double)sum, qq = (double)sumsq;
    for (int off = 32; off > 0; off >>= 1) {
        s  += __shfl_down(s, off);
        qq += __shfl_down(qq, off);
    }
    __shared__ double wsum[4], wsq[4];
    const int wid = tid >> 6, lane = tid & 63;
    if (lane == 0) { wsum[wid] = s; wsq[wid] = qq; }
    __syncthreads();
    if (tid == 0) {
        double S = wsum[0] + wsum[1] + wsum[2] + wsum[3];
        double Q = wsq[0] + wsq[1] + wsq[2] + wsq[3];
        partials[(size_t)(b * 4 + mg) * 2]     = S;
        partials[(size_t)(b * 4 + mg) * 2 + 1] = Q;
    }
}

// ---------------- kernel 4: normalize (full GPU, float4) ----------------
__global__ void norm_kernel(float* __restrict__ out, const double* __restrict__ partials) {
    __shared__ float sh[2];
    const int b = blockIdx.x;
    if (threadIdx.x == 0) {
        double S = 0.0, Q = 0.0;
#pragma unroll
        for (int gg = 0; gg < 4; ++gg) {
            S += partials[(size_t)(b * 4 + gg) * 2];
            Q += partials[(size_t)(b * 4 + gg) * 2 + 1];
        }
        const double n = (double)(NMELS * TFRAMES);
        double mean = S / n;
        double var  = (Q - n * mean * mean) / (n - 1.0);
        double sd   = sqrt(var > 0.0 ? var : 0.0);
        sh[0] = (float)mean;
        sh[1] = (float)(1.0 / (sd + 1e-6));
    }
    __syncthreads();
    const int i4 = blockIdx.y * 256 + threadIdx.x;
    if (i4 >= NMELS * TFRAMES / 4) return;          // 12832
    const float mean = sh[0], inv = sh[1];
    float4* o = (float4*)(out + (size_t)b * NMELS * TFRAMES);
    float4 vv = o[i4];
    vv.x = (vv.x - mean) * inv;
    vv.y = (vv.y - mean) * inv;
    vv.z = (vv.z - mean) * inv;
    vv.w = (vv.w - mean) * inv;
    o[i4] = vv;
}

// ---------------- launch ----------------
extern "C" void kernel_launch(void* const* d_in, const int* in_sizes, int n_in,
                              void* d_out, int out_size, void* d_ws, size_t ws_size,
                              hipStream_t stream) {
    const float* x = (const float*)d_in[0];
    float* out = (float*)d_out;
    float* ws  = (float*)d_ws;

    float*  win     = ws + WS_WIN;
    float*  fbpackT = ws + WS_FBP;
    int*    fstart  = (int*)(ws + WS_FS);
    float2* T1      = (float2*)(ws + WS_T1);
    float2* T2      = (float2*)(ws + WS_T2);
    double* parts   = (double*)(ws + WS_PART);
    float*  mel     = ws + WS_MEL;

    prep_kernel<<<dim3(9), dim3(256), 0, stream>>>(win, fbpackT, fstart, T1, T2);
    fft_mel_kernel<<<dim3((NB / 2) * TFRAMES), dim3(64), 0, stream>>>(
        x, win, T1, T2, fbpackT, fstart, mel);
    pcen_kernel<<<dim3(NB * 4), dim3(256), 0, stream>>>(mel, out, parts);
    norm_kernel<<<dim3(NB, 51), dim3(256), 0, stream>>>(out, parts);
}